// Round 7
// baseline (60.161 us; speedup 1.0000x reference)
//
#include <hip/hip_runtime.h>

// NCuts loss: seg [8,4,224,224], padded_seg [8,4,232,232],
// weight [8,1,224,224,9,9], sum_weight [8,1,224,224] -> out[8] (fp32)
//
// stage1: one persistent block per image row (8*224 = 1792 blocks).
//  - psg row-slab staged ONCE per block in CLASS-INTERLEAVED layout
//    [9 rows][232 cols][4 classes] -> one ds_read_b128 per tap yields all
//    4 class values (was 4x ds_read_b32). Staged via coalesced scalar
//    global loads + contiguous ds_write_b128 (conflict-free).
//  - weight slab double-buffered (2 x 56px*81), prefetched one tile ahead
//    via global_load_lds (zero VGPR round-trip). Prefetch issued at loop
//    top; the post-compute __syncthreads drains vmcnt, so HBM latency
//    hides under the tap loop.
//  - 81 taps split across 4 waves with compile-time indices.

constexpr int NN  = 8;
constexpr int KK  = 4;
constexpr int HH  = 224;
constexpr int WW  = 224;
constexpr int PAD = 4;                   // RADIUS-1
constexpr int HP  = HH + 2 * PAD;        // 232
constexpr int WP  = WW + 2 * PAD;        // 232
constexpr int NWIN = 81;
constexpr int PIX = HH * WW;             // 50176
constexpr int TPB = 256;
constexpr int PPB = 56;                  // pixels per tile
constexpr int TPR = WW / PPB;            // 4 tiles per row
constexpr int BPI = HH * TPR;            // 896 tiles per image (stage2)
constexpr int PLANE = HP * WP;           // 53824
constexpr int PSG_N = 9 * WP;            // 2088 (m,col) sites per row-slab
constexpr int WSLAB = PPB * NWIN;        // 4536 floats per weight tile
constexpr int WF4 = WSLAB / 4;           // 1134 float4

#define GLL16(gptr, lptr)                                            \
    __builtin_amdgcn_global_load_lds(                                \
        (const __attribute__((address_space(1))) void*)(gptr),       \
        (__attribute__((address_space(3))) void*)(lptr), 16, 0, 0)

template<int T0, int T1>
__device__ inline void do_taps(const float* __restrict__ lwp,
                               const float* __restrict__ psl,
                               float acc[KK]) {
#pragma unroll
    for (int t = T0; t < T1; ++t) {
        const int m = t / 9;
        const int j = t - 9 * m;          // compile-time after unroll
        const float wv = lwp[t];                                  // ds_read_b32
        const float4 p4 = *(const float4*)(psl + (m * WP + j) * 4); // ds_read_b128
        acc[0] += p4.x * wv;
        acc[1] += p4.y * wv;
        acc[2] += p4.z * wv;
        acc[3] += p4.w * wv;
    }
}

__global__ __launch_bounds__(TPB) void ncuts_stage1(
    const float* __restrict__ seg, const float* __restrict__ pseg,
    const float* __restrict__ wgt, const float* __restrict__ swgt,
    float* __restrict__ part)
{
    const int b    = blockIdx.x;             // n*224 + h
    const int n    = b / HH;
    const int h    = b - n * HH;
    const int tid  = threadIdx.x;
    const int wv_  = tid >> 6;
    const int lane = tid & 63;

    __shared__ float lds_w[2 * WSLAB];       // 36288 B (double buffer)
    __shared__ float psg_lds[PSG_N * KK];    // 33408 B, [m][col][class]
    __shared__ float accB[PPB * 17];         // 3808 B, stride 17 -> no conflicts

    // ---- weight tile stager: global_load_lds, linear LDS dest ----
    auto stage_w = [&](int buf, int tt) {
        const float4* wsrc = (const float4*)(
            wgt + ((size_t)n * PIX + (size_t)h * WW + tt * PPB) * NWIN);
        float* base = lds_w + buf * WSLAB;
#pragma unroll
        for (int k = 0; k < 5; ++k) {
            const int i = k * TPB + tid;
            if (i < WF4)
                GLL16(wsrc + i, base + ((k * TPB + (tid >> 6) * 64) << 2));
        }
    };

    stage_w(0, 0);                            // async: weight tile 0

    // ---- psg row-slab, class-interleaved [m][col][c] ----
    {
        const size_t nb = (size_t)n * KK * PLANE;
#pragma unroll
        for (int k = 0; k < 9; ++k) {
            const int idx = k * TPB + tid;    // (m,col) site
            if (idx < PSG_N) {
                const int m   = idx / WP;
                const int col = idx - m * WP;
                const float* g = pseg + nb + (size_t)(h + m) * WP + col;
                float4 v;
                v.x = g[0];
                v.y = g[PLANE];
                v.z = g[2 * (size_t)PLANE];
                v.w = g[3 * (size_t)PLANE];
                *(float4*)(psg_lds + (size_t)idx * 4) = v;   // contiguous b128
            }
        }
    }

    // ---- hoist seg / sum_weight for all 4 tiles into registers ----
    const int cc = wv_;                      // epilogue class of this wave
    float segv[TPR] = {0.f, 0.f, 0.f, 0.f};
    float swv[TPR]  = {0.f, 0.f, 0.f, 0.f};
    if (lane < PPB) {
#pragma unroll
        for (int tt = 0; tt < TPR; ++tt) {
            const int p = h * WW + tt * PPB + lane;
            segv[tt] = seg[(size_t)n * KK * PIX + (size_t)cc * PIX + p];
            swv[tt]  = swgt[(size_t)n * PIX + p];
        }
    }

    __syncthreads();   // drains vmcnt/lgkm: psg slab + weight tile 0 landed

    int cur = 0;
#pragma unroll
    for (int tt = 0; tt < TPR; ++tt) {
        // ---- async prefetch of next weight tile into the other buffer ----
        if (tt + 1 < TPR) stage_w(cur ^ 1, tt + 1);

        // ---- compute tile tt from LDS ----
        float acc[KK] = {0.f, 0.f, 0.f, 0.f};
        if (lane < PPB) {
            const float* lwp = lds_w + cur * WSLAB + lane * NWIN;
            const float* psl = psg_lds + (tt * PPB + lane) * 4;
            switch (wv_) {
                case 0:  do_taps<0, 20>(lwp, psl, acc); break;
                case 1:  do_taps<20, 40>(lwp, psl, acc); break;
                case 2:  do_taps<40, 60>(lwp, psl, acc); break;
                default: do_taps<60, 81>(lwp, psl, acc); break;
            }
#pragma unroll
            for (int c = 0; c < KK; ++c) accB[lane * 17 + wv_ * 4 + c] = acc[c];
        }
        __syncthreads();   // accB visible; prefetch drained (hidden under compute)

        // ---- epilogue: wave cc owns class cc; lanes = pixels ----
        float A = 0.f, V = 0.f;
        if (lane < PPB) {
            const float r = accB[lane * 17 + cc]     + accB[lane * 17 + 4 + cc] +
                            accB[lane * 17 + 8 + cc] + accB[lane * 17 + 12 + cc];
            A = r * segv[tt];
            V = swv[tt] * segv[tt];
        }
#pragma unroll
        for (int off = 32; off > 0; off >>= 1) {
            A += __shfl_down(A, off, 64);
            V += __shfl_down(V, off, 64);
        }
        if (lane == 0) {
            const size_t tg = (size_t)b * TPR + tt;   // (n*224+h)*4+tt
            part[tg * 8 + cc]     = A;
            part[tg * 8 + 4 + cc] = V;
        }
        __syncthreads();   // epilogue accB reads done before next tile rewrites
        cur ^= 1;
    }
}

__global__ __launch_bounds__(TPB) void ncuts_stage2(
    const float* __restrict__ part, float* __restrict__ out)
{
    const int n   = blockIdx.x;
    const int tid = threadIdx.x;

    float vals[8] = {0.f, 0.f, 0.f, 0.f, 0.f, 0.f, 0.f, 0.f};
    for (int bb = tid; bb < BPI; bb += TPB) {
        const float* q = part + ((size_t)(n * BPI + bb)) * 8;
#pragma unroll
        for (int i = 0; i < 8; ++i) vals[i] += q[i];
    }

    __shared__ float lred[4][8];
    const int lane = tid & 63;
    const int wv_  = tid >> 6;
#pragma unroll
    for (int i = 0; i < 8; ++i) {
        float v = vals[i];
#pragma unroll
        for (int off = 32; off > 0; off >>= 1) v += __shfl_down(v, off, 64);
        if (lane == 0) lred[wv_][i] = v;
    }
    __syncthreads();
    if (tid == 0) {
        float assoc = 0.f;
#pragma unroll
        for (int k = 0; k < 4; ++k) {
            const float A = lred[0][k] + lred[1][k] + lred[2][k] + lred[3][k];
            const float V = lred[0][4 + k] + lred[1][4 + k] + lred[2][4 + k] + lred[3][4 + k];
            assoc += A / V;
        }
        out[n] = 4.0f - assoc;
    }
}

extern "C" void kernel_launch(void* const* d_in, const int* in_sizes, int n_in,
                              void* d_out, int out_size, void* d_ws, size_t ws_size,
                              hipStream_t stream) {
    const float* seg  = (const float*)d_in[0];
    const float* pseg = (const float*)d_in[1];
    const float* wgt  = (const float*)d_in[2];
    const float* swgt = (const float*)d_in[3];
    float* out  = (float*)d_out;
    float* part = (float*)d_ws;   // 7168 tiles * 8 floats = 229376 B

    ncuts_stage1<<<NN * HH, TPB, 0, stream>>>(seg, pseg, wgt, swgt, part);
    ncuts_stage2<<<NN, TPB, 0, stream>>>(part, out);
}

// Round 8
// 49.053 us; speedup vs baseline: 1.2264x; 1.2264x over previous
//
#include <hip/hip_runtime.h>

// NCuts loss: seg [8,4,224,224], padded_seg [8,4,232,232],
// weight [8,1,224,224,9,9], sum_weight [8,1,224,224] -> out[8] (fp32)
//
// stage1: one persistent block per image row (8*224 = 1792 blocks).
//  - psg row-slab ([4 classes][9 rows][232 cols]) staged ONCE per block via
//    global_load_lds (round-6 layout: separated classes, b32 tap reads,
//    proven 0 bank conflicts; the round-7 b128-interleave showed 1.1e7
//    conflicts and regressed -- reverted).
//  - weight slab double-buffered (2 x 56px*81), prefetched one tile ahead
//    via global_load_lds; post-compute __syncthreads drains vmcnt so HBM
//    latency hides under the tap loop.
//  - NEW: no per-tile epilogue. Each wave folds its tap-partial acc[c] into
//    per-wave register accumulators rA[c] (A is linear in the wave-partials),
//    rV computed once by wave 0. ONE cross-lane/cross-wave reduction per
//    block. Removes ~320 LDS ops + 4 barriers per block vs round 6.

constexpr int NN  = 8;
constexpr int KK  = 4;
constexpr int HH  = 224;
constexpr int WW  = 224;
constexpr int PAD = 4;                   // RADIUS-1
constexpr int HP  = HH + 2 * PAD;        // 232
constexpr int WP  = WW + 2 * PAD;        // 232
constexpr int NWIN = 81;
constexpr int PIX = HH * WW;             // 50176
constexpr int TPB = 256;
constexpr int PPB = 56;                  // pixels per tile
constexpr int TPR = WW / PPB;            // 4 tiles per row
constexpr int PLANE = HP * WP;           // 53824
constexpr int PSG_CLS = 9 * WP;          // 2088 floats per class row-tile
constexpr int PSGF4 = KK * PSG_CLS / 4;  // 2088 float4
constexpr int WSLAB = PPB * NWIN;        // 4536 floats per weight tile
constexpr int WF4 = WSLAB / 4;           // 1134 float4

#define GLL16(gptr, lptr)                                            \
    __builtin_amdgcn_global_load_lds(                                \
        (const __attribute__((address_space(1))) void*)(gptr),       \
        (__attribute__((address_space(3))) void*)(lptr), 16, 0, 0)

template<int T0, int T1>
__device__ inline void do_taps(const float* __restrict__ lwp,
                               const float* __restrict__ psl,
                               float acc[KK]) {
#pragma unroll
    for (int t = T0; t < T1; ++t) {
        const int m = t / 9;
        const int j = t - 9 * m;          // compile-time after unroll
        const float wv = lwp[t];          // ds_read_b32, immediate offset
#pragma unroll
        for (int c = 0; c < KK; ++c)
            acc[c] += psl[c * PSG_CLS + m * WP + j] * wv;
    }
}

__global__ __launch_bounds__(TPB) void ncuts_stage1(
    const float* __restrict__ seg, const float* __restrict__ pseg,
    const float* __restrict__ wgt, const float* __restrict__ swgt,
    float* __restrict__ part)
{
    const int b    = blockIdx.x;             // n*224 + h
    const int n    = b / HH;
    const int h    = b - n * HH;
    const int tid  = threadIdx.x;
    const int wv_  = tid >> 6;
    const int lane = tid & 63;

    __shared__ float lds_w[2 * WSLAB];       // 36288 B (double buffer)
    __shared__ float psg_lds[KK * PSG_CLS];  // 33408 B (whole row, all classes)
    __shared__ float lred[4][8];

    // ---- weight tile stager: global_load_lds, linear LDS dest ----
    auto stage_w = [&](int buf, int tt) {
        const float4* wsrc = (const float4*)(
            wgt + ((size_t)n * PIX + (size_t)h * WW + tt * PPB) * NWIN);
        float* base = lds_w + buf * WSLAB;
#pragma unroll
        for (int k = 0; k < 5; ++k) {
            const int i = k * TPB + tid;
            if (i < WF4)
                GLL16(wsrc + i, base + ((k * TPB + (tid >> 6) * 64) << 2));
        }
    };

    stage_w(0, 0);                            // async: weight tile 0

    // ---- psg row-slab (separated classes), via global_load_lds ----
    {
        const size_t nb = (size_t)n * KK * PLANE;
#pragma unroll
        for (int k = 0; k < 9; ++k) {
            const int i = k * TPB + tid;
            if (i < PSGF4) {
                const int c  = i / 522;          // 522 = PSG_CLS/4
                const int r  = i - 522 * c;
                const int m  = r / 58;           // 58 = WP/4
                const int c4 = r - 58 * m;
                const float* src = pseg + nb + (size_t)c * PLANE +
                                   (size_t)(h + m) * WP + c4 * 4;
                GLL16(src, psg_lds + ((k * TPB + (tid >> 6) * 64) << 2));
            }
        }
    }

    // ---- hoist seg (all classes) / sum_weight into registers ----
    float segv[KK][TPR];
    float swv[TPR];
#pragma unroll
    for (int c = 0; c < KK; ++c)
#pragma unroll
        for (int tt = 0; tt < TPR; ++tt) segv[c][tt] = 0.f;
#pragma unroll
    for (int tt = 0; tt < TPR; ++tt) swv[tt] = 0.f;
    if (lane < PPB) {
#pragma unroll
        for (int tt = 0; tt < TPR; ++tt) {
            const int p = h * WW + tt * PPB + lane;
#pragma unroll
            for (int c = 0; c < KK; ++c)
                segv[c][tt] = seg[(size_t)n * KK * PIX + (size_t)c * PIX + p];
            swv[tt] = swgt[(size_t)n * PIX + p];
        }
    }

    // ---- per-wave register accumulators ----
    float rA[KK] = {0.f, 0.f, 0.f, 0.f};
    float rV[KK] = {0.f, 0.f, 0.f, 0.f};
    if (wv_ == 0) {
#pragma unroll
        for (int tt = 0; tt < TPR; ++tt)
#pragma unroll
            for (int c = 0; c < KK; ++c)
                rV[c] += swv[tt] * segv[c][tt];
    }

    __syncthreads();   // drains vmcnt: psg slab + weight tile 0 landed

    int cur = 0;
#pragma unroll
    for (int tt = 0; tt < TPR; ++tt) {
        // ---- async prefetch of next weight tile into the other buffer ----
        if (tt + 1 < TPR) stage_w(cur ^ 1, tt + 1);

        // ---- compute tile tt from LDS; fold into rA (no LDS epilogue) ----
        if (lane < PPB) {
            float acc[KK] = {0.f, 0.f, 0.f, 0.f};
            const float* lwp = lds_w + cur * WSLAB + lane * NWIN;
            const float* psl = psg_lds + tt * PPB + lane;
            switch (wv_) {
                case 0:  do_taps<0, 20>(lwp, psl, acc); break;
                case 1:  do_taps<20, 40>(lwp, psl, acc); break;
                case 2:  do_taps<40, 60>(lwp, psl, acc); break;
                default: do_taps<60, 81>(lwp, psl, acc); break;
            }
#pragma unroll
            for (int c = 0; c < KK; ++c) rA[c] += acc[c] * segv[c][tt];
        }
        __syncthreads();   // prefetch drained (hidden under compute); buf free
        cur ^= 1;
    }

    // ---- single block-end reduction ----
    float vals[8] = { rA[0], rA[1], rA[2], rA[3], rV[0], rV[1], rV[2], rV[3] };
#pragma unroll
    for (int i = 0; i < 8; ++i) {
        float v = vals[i];
#pragma unroll
        for (int off = 32; off > 0; off >>= 1) v += __shfl_down(v, off, 64);
        if (lane == 0) lred[wv_][i] = v;
    }
    __syncthreads();
    if (tid < 8) {
        part[(size_t)b * 8 + tid] =
            lred[0][tid] + lred[1][tid] + lred[2][tid] + lred[3][tid];
    }
}

__global__ __launch_bounds__(TPB) void ncuts_stage2(
    const float* __restrict__ part, float* __restrict__ out)
{
    const int n   = blockIdx.x;
    const int tid = threadIdx.x;

    float vals[8] = {0.f, 0.f, 0.f, 0.f, 0.f, 0.f, 0.f, 0.f};
    for (int bb = tid; bb < HH; bb += TPB) {        // 224 entries per image
        const float* q = part + ((size_t)(n * HH + bb)) * 8;
#pragma unroll
        for (int i = 0; i < 8; ++i) vals[i] += q[i];
    }

    __shared__ float lred[4][8];
    const int lane = tid & 63;
    const int wv_  = tid >> 6;
#pragma unroll
    for (int i = 0; i < 8; ++i) {
        float v = vals[i];
#pragma unroll
        for (int off = 32; off > 0; off >>= 1) v += __shfl_down(v, off, 64);
        if (lane == 0) lred[wv_][i] = v;
    }
    __syncthreads();
    if (tid == 0) {
        float assoc = 0.f;
#pragma unroll
        for (int k = 0; k < 4; ++k) {
            const float A = lred[0][k] + lred[1][k] + lred[2][k] + lred[3][k];
            const float V = lred[0][4 + k] + lred[1][4 + k] + lred[2][4 + k] + lred[3][4 + k];
            assoc += A / V;
        }
        out[n] = 4.0f - assoc;
    }
}

extern "C" void kernel_launch(void* const* d_in, const int* in_sizes, int n_in,
                              void* d_out, int out_size, void* d_ws, size_t ws_size,
                              hipStream_t stream) {
    const float* seg  = (const float*)d_in[0];
    const float* pseg = (const float*)d_in[1];
    const float* wgt  = (const float*)d_in[2];
    const float* swgt = (const float*)d_in[3];
    float* out  = (float*)d_out;
    float* part = (float*)d_ws;   // 1792 blocks * 8 floats = 57344 B

    ncuts_stage1<<<NN * HH, TPB, 0, stream>>>(seg, pseg, wgt, swgt, part);
    ncuts_stage2<<<NN, TPB, 0, stream>>>(part, out);
}

// Round 9
// 46.553 us; speedup vs baseline: 1.2923x; 1.0537x over previous
//
#include <hip/hip_runtime.h>

// NCuts loss: seg [8,4,224,224], padded_seg [8,4,232,232],
// weight [8,1,224,224,9,9], sum_weight [8,1,224,224] -> out[8] (fp32)
//
// stage1: one persistent block per image row (8*224 = 1792 blocks),
// TPB=512 (8 waves). LDS (73.7KB) allows 2 blocks/CU -> 16 waves/CU
// (was 8 at TPB=256): doubles latency-hiding TLP at identical LDS
// footprint and total work. 81 taps split across 8 waves (~10 each),
// compile-time indices. Weight slab double-buffered via global_load_lds
// (prefetch 1 tile ahead); psg row-slab staged once per block; register
// rA accumulation; single block-end reduction. All layouts proven
// conflict-free (rounds 6/8: SQ_LDS_BANK_CONFLICT = 0).

constexpr int NN  = 8;
constexpr int KK  = 4;
constexpr int HH  = 224;
constexpr int WW  = 224;
constexpr int PAD = 4;                   // RADIUS-1
constexpr int HP  = HH + 2 * PAD;        // 232
constexpr int WP  = WW + 2 * PAD;        // 232
constexpr int NWIN = 81;
constexpr int PIX = HH * WW;             // 50176
constexpr int TPB = 512;                 // 8 waves
constexpr int PPB = 56;                  // pixels per tile
constexpr int TPR = WW / PPB;            // 4 tiles per row
constexpr int PLANE = HP * WP;           // 53824
constexpr int PSG_CLS = 9 * WP;          // 2088 floats per class row-tile
constexpr int PSGF4 = KK * PSG_CLS / 4;  // 2088 float4
constexpr int WSLAB = PPB * NWIN;        // 4536 floats per weight tile
constexpr int WF4 = WSLAB / 4;           // 1134 float4

#define GLL16(gptr, lptr)                                            \
    __builtin_amdgcn_global_load_lds(                                \
        (const __attribute__((address_space(1))) void*)(gptr),       \
        (__attribute__((address_space(3))) void*)(lptr), 16, 0, 0)

template<int T0, int T1>
__device__ inline void do_taps(const float* __restrict__ lwp,
                               const float* __restrict__ psl,
                               float acc[KK]) {
#pragma unroll
    for (int t = T0; t < T1; ++t) {
        const int m = t / 9;
        const int j = t - 9 * m;          // compile-time after unroll
        const float wv = lwp[t];          // ds_read_b32, immediate offset
#pragma unroll
        for (int c = 0; c < KK; ++c)
            acc[c] += psl[c * PSG_CLS + m * WP + j] * wv;
    }
}

__global__ __launch_bounds__(TPB) void ncuts_stage1(
    const float* __restrict__ seg, const float* __restrict__ pseg,
    const float* __restrict__ wgt, const float* __restrict__ swgt,
    float* __restrict__ part)
{
    const int b    = blockIdx.x;             // n*224 + h
    const int n    = b / HH;
    const int h    = b - n * HH;
    const int tid  = threadIdx.x;
    const int wv_  = tid >> 6;               // 0..7
    const int lane = tid & 63;

    __shared__ float lds_w[2 * WSLAB];       // 36288 B (double buffer)
    __shared__ float psg_lds[KK * PSG_CLS];  // 33408 B (whole row, all classes)
    __shared__ float lred[8][8];

    // ---- weight tile stager: global_load_lds, linear LDS dest ----
    auto stage_w = [&](int buf, int tt) {
        const float4* wsrc = (const float4*)(
            wgt + ((size_t)n * PIX + (size_t)h * WW + tt * PPB) * NWIN);
        float* base = lds_w + buf * WSLAB;
#pragma unroll
        for (int k = 0; k < 3; ++k) {        // 3*512 >= 1134
            const int i = k * TPB + tid;
            if (i < WF4)
                GLL16(wsrc + i, base + ((k * TPB + wv_ * 64) << 2));
        }
    };

    stage_w(0, 0);                            // async: weight tile 0

    // ---- psg row-slab (separated classes), via global_load_lds ----
    {
        const size_t nb = (size_t)n * KK * PLANE;
#pragma unroll
        for (int k = 0; k < 5; ++k) {        // 5*512 >= 2088
            const int i = k * TPB + tid;
            if (i < PSGF4) {
                const int c  = i / 522;          // 522 = PSG_CLS/4
                const int r  = i - 522 * c;
                const int m  = r / 58;           // 58 = WP/4
                const int c4 = r - 58 * m;
                const float* src = pseg + nb + (size_t)c * PLANE +
                                   (size_t)(h + m) * WP + c4 * 4;
                GLL16(src, psg_lds + ((k * TPB + wv_ * 64) << 2));
            }
        }
    }

    // ---- hoist seg (all classes) / sum_weight into registers ----
    float segv[KK][TPR];
    float swv[TPR];
#pragma unroll
    for (int c = 0; c < KK; ++c)
#pragma unroll
        for (int tt = 0; tt < TPR; ++tt) segv[c][tt] = 0.f;
#pragma unroll
    for (int tt = 0; tt < TPR; ++tt) swv[tt] = 0.f;
    if (lane < PPB) {
#pragma unroll
        for (int tt = 0; tt < TPR; ++tt) {
            const int p = h * WW + tt * PPB + lane;
#pragma unroll
            for (int c = 0; c < KK; ++c)
                segv[c][tt] = seg[(size_t)n * KK * PIX + (size_t)c * PIX + p];
            swv[tt] = swgt[(size_t)n * PIX + p];
        }
    }

    // ---- per-wave register accumulators ----
    float rA[KK] = {0.f, 0.f, 0.f, 0.f};
    float rV[KK] = {0.f, 0.f, 0.f, 0.f};
    if (wv_ == 0) {
#pragma unroll
        for (int tt = 0; tt < TPR; ++tt)
#pragma unroll
            for (int c = 0; c < KK; ++c)
                rV[c] += swv[tt] * segv[c][tt];
    }

    __syncthreads();   // drains vmcnt: psg slab + weight tile 0 landed

    int cur = 0;
#pragma unroll
    for (int tt = 0; tt < TPR; ++tt) {
        // ---- async prefetch of next weight tile into the other buffer ----
        if (tt + 1 < TPR) stage_w(cur ^ 1, tt + 1);

        // ---- compute tile tt from LDS; fold into rA ----
        if (lane < PPB) {
            float acc[KK] = {0.f, 0.f, 0.f, 0.f};
            const float* lwp = lds_w + cur * WSLAB + lane * NWIN;
            const float* psl = psg_lds + tt * PPB + lane;
            switch (wv_) {
                case 0:  do_taps<0, 10>(lwp, psl, acc); break;
                case 1:  do_taps<10, 20>(lwp, psl, acc); break;
                case 2:  do_taps<20, 30>(lwp, psl, acc); break;
                case 3:  do_taps<30, 40>(lwp, psl, acc); break;
                case 4:  do_taps<40, 50>(lwp, psl, acc); break;
                case 5:  do_taps<50, 60>(lwp, psl, acc); break;
                case 6:  do_taps<60, 70>(lwp, psl, acc); break;
                default: do_taps<70, 81>(lwp, psl, acc); break;
            }
#pragma unroll
            for (int c = 0; c < KK; ++c) rA[c] += acc[c] * segv[c][tt];
        }
        __syncthreads();   // prefetch drained (hidden under compute); buf free
        cur ^= 1;
    }

    // ---- single block-end reduction ----
    float vals[8] = { rA[0], rA[1], rA[2], rA[3], rV[0], rV[1], rV[2], rV[3] };
#pragma unroll
    for (int i = 0; i < 8; ++i) {
        float v = vals[i];
#pragma unroll
        for (int off = 32; off > 0; off >>= 1) v += __shfl_down(v, off, 64);
        if (lane == 0) lred[wv_][i] = v;
    }
    __syncthreads();
    if (tid < 8) {
        float s = 0.f;
#pragma unroll
        for (int w = 0; w < 8; ++w) s += lred[w][tid];
        part[(size_t)b * 8 + tid] = s;
    }
}

__global__ __launch_bounds__(256) void ncuts_stage2(
    const float* __restrict__ part, float* __restrict__ out)
{
    const int n   = blockIdx.x;
    const int tid = threadIdx.x;

    float vals[8] = {0.f, 0.f, 0.f, 0.f, 0.f, 0.f, 0.f, 0.f};
    for (int bb = tid; bb < HH; bb += 256) {        // 224 entries per image
        const float* q = part + ((size_t)(n * HH + bb)) * 8;
#pragma unroll
        for (int i = 0; i < 8; ++i) vals[i] += q[i];
    }

    __shared__ float lred[4][8];
    const int lane = tid & 63;
    const int wv_  = tid >> 6;
#pragma unroll
    for (int i = 0; i < 8; ++i) {
        float v = vals[i];
#pragma unroll
        for (int off = 32; off > 0; off >>= 1) v += __shfl_down(v, off, 64);
        if (lane == 0) lred[wv_][i] = v;
    }
    __syncthreads();
    if (tid == 0) {
        float assoc = 0.f;
#pragma unroll
        for (int k = 0; k < 4; ++k) {
            const float A = lred[0][k] + lred[1][k] + lred[2][k] + lred[3][k];
            const float V = lred[0][4 + k] + lred[1][4 + k] + lred[2][4 + k] + lred[3][4 + k];
            assoc += A / V;
        }
        out[n] = 4.0f - assoc;
    }
}

extern "C" void kernel_launch(void* const* d_in, const int* in_sizes, int n_in,
                              void* d_out, int out_size, void* d_ws, size_t ws_size,
                              hipStream_t stream) {
    const float* seg  = (const float*)d_in[0];
    const float* pseg = (const float*)d_in[1];
    const float* wgt  = (const float*)d_in[2];
    const float* swgt = (const float*)d_in[3];
    float* out  = (float*)d_out;
    float* part = (float*)d_ws;   // 1792 blocks * 8 floats = 57344 B

    ncuts_stage1<<<NN * HH, TPB, 0, stream>>>(seg, pseg, wgt, swgt, part);
    ncuts_stage2<<<NN, 256, 0, stream>>>(part, out);
}

// Round 10
// 42.414 us; speedup vs baseline: 1.4184x; 1.0976x over previous
//
#include <hip/hip_runtime.h>

// NCuts loss: seg [8,4,224,224], padded_seg [8,4,232,232],
// weight [8,1,224,224,9,9], sum_weight [8,1,224,224] -> out[8] (fp32)
//
// stage1: PERSISTENT blocks. Grid = 256 = #CUs; LDS 92KB forces 1 block/CU
// so blocks spread across all CUs. Each block owns 7 consecutive image rows
// (8*32*7 = 1792). Per block:
//  - weight: 28 tiles (56px*81) fully contiguous 507KB, streamed through the
//    proven 2-buffer global_load_lds pipeline, prefetch 1 tile ahead,
//    continuous across row boundaries (prologue/drain paid ONCE, not 7x).
//  - psg: rolling 15-row window [15][4][232] in LDS; prologue stages rows
//    h0..h0+8, then each step stages ONE new row (3.7KB) -> psg re-fetch
//    drops ~4x vs per-row blocks.
//  - tap loop verbatim from rounds 8/9 (81 taps over 8 waves, compile-time
//    tap indices, b32 reads, 0 bank conflicts), register rA accumulation,
//    single block-end reduction.

constexpr int NN  = 8;
constexpr int KK  = 4;
constexpr int HH  = 224;
constexpr int WW  = 224;
constexpr int PAD = 4;                   // RADIUS-1
constexpr int HP  = HH + 2 * PAD;        // 232
constexpr int WP  = WW + 2 * PAD;        // 232
constexpr int NWIN = 81;
constexpr int PIX = HH * WW;             // 50176
constexpr int TPB = 512;                 // 8 waves
constexpr int PPB = 56;                  // pixels per tile
constexpr int TPR = WW / PPB;            // 4 tiles per row
constexpr int RPB = 7;                   // rows per block
constexpr int GPI = HH / RPB;            // 32 row-groups per image
constexpr int NBLK = NN * GPI;           // 256 blocks == #CUs
constexpr int PLANE = HP * WP;           // 53824
constexpr int ROWF = KK * WP;            // 928 floats per psg row-slot
constexpr int ROWF4 = ROWF / 4;          // 232
constexpr int NSLOT = 15;                // psg rows resident: s..s+8, staged to s+9..14
constexpr int PRO_F4 = 9 * ROWF4;        // 2088 float4 prologue psg
constexpr int WSLAB = PPB * NWIN;        // 4536 floats per weight tile
constexpr int WF4 = WSLAB / 4;           // 1134 float4
constexpr int NTILE = RPB * TPR;         // 28 weight tiles per block

#define GLL16(gptr, lptr)                                            \
    __builtin_amdgcn_global_load_lds(                                \
        (const __attribute__((address_space(1))) void*)(gptr),       \
        (__attribute__((address_space(3))) void*)(lptr), 16, 0, 0)

template<int T0, int T1>
__device__ inline void do_taps(const float* __restrict__ lwp,
                               const float* __restrict__ psg,
                               const unsigned idx[9],
                               float acc[KK]) {
#pragma unroll
    for (int t = T0; t < T1; ++t) {
        const int m = t / 9;
        const int j = t - 9 * m;          // compile-time after unroll
        const float wv = lwp[t];          // ds_read_b32, immediate offset
#pragma unroll
        for (int c = 0; c < KK; ++c)
            acc[c] += psg[idx[m] + c * WP + j] * wv;
    }
}

__global__ __launch_bounds__(TPB) void ncuts_stage1(
    const float* __restrict__ seg, const float* __restrict__ pseg,
    const float* __restrict__ wgt, const float* __restrict__ swgt,
    float* __restrict__ part)
{
    const int b    = blockIdx.x;             // n*32 + row-group
    const int n    = b >> 5;
    const int h0   = (b & 31) * RPB;         // first image row of this block
    const int tid  = threadIdx.x;
    const int wv_  = tid >> 6;               // 0..7
    const int lane = tid & 63;

    __shared__ float lds_w[2 * WSLAB];       // 36288 B (double buffer)
    __shared__ float psg_lds[NSLOT * ROWF];  // 55680 B rolling window
    __shared__ float lred[8][8];             // 256 B  -> total 92224 B (1 blk/CU)

    const size_t nb = (size_t)n * KK * PLANE;
    const float* wbase = wgt + ((size_t)n * PIX + (size_t)h0 * WW) * NWIN;

    // ---- weight tile stager: global_load_lds, linear LDS dest ----
    auto stage_w = [&](int buf, int ti) {
        const float4* wsrc = (const float4*)(wbase + (size_t)ti * WSLAB);
        float* base = lds_w + buf * WSLAB;
#pragma unroll
        for (int k = 0; k < 3; ++k) {        // 3*512 >= 1134
            const int i = k * TPB + tid;
            if (i < WF4)
                GLL16(wsrc + i, base + ((k * TPB + wv_ * 64) << 2));
        }
    };

    // ---- one psg row (4 classes x 232 cols) into slot ----
    auto stage_psg_row = [&](int slot, int rglob) {
        if (tid < ROWF4) {
            const int c  = tid / 58;         // 58 = WP/4
            const int c4 = tid - c * 58;
            const float* src = pseg + nb + (size_t)c * PLANE +
                               (size_t)rglob * WP + c4 * 4;
            GLL16(src, psg_lds + slot * ROWF + ((tid & ~63) << 2));
        }
    };

    stage_w(0, 0);                            // async: weight tile 0

    // ---- prologue psg: rows h0..h0+8 -> slots 0..8 (linear region) ----
#pragma unroll
    for (int k = 0; k < 5; ++k) {            // 5*512 >= 2088
        const int i = k * TPB + tid;
        if (i < PRO_F4) {
            const int slot = i / ROWF4;
            const int rem  = i - slot * ROWF4;
            const int c    = rem / 58;
            const int c4   = rem - c * 58;
            const float* src = pseg + nb + (size_t)c * PLANE +
                               (size_t)(h0 + slot) * WP + c4 * 4;
            GLL16(src, psg_lds + ((k * TPB + (tid & ~63)) << 2));
        }
    }

    float rA[KK] = {0.f, 0.f, 0.f, 0.f};
    float rV[KK] = {0.f, 0.f, 0.f, 0.f};

    __syncthreads();   // drains vmcnt: psg rows 0..8 + weight tile 0 landed

    int cur = 0;
#pragma unroll 1
    for (int s = 0; s < RPB; ++s) {
        const int h = h0 + s;

        // ---- stage ONE new psg row (slot s+9) for the next step ----
        if (s + 1 < RPB) stage_psg_row(s + 9, h + 9);

        // ---- seg / sum_weight for this row (20 coalesced scalar loads) ----
        float segv[KK][TPR];
        float swv[TPR];
#pragma unroll
        for (int c = 0; c < KK; ++c)
#pragma unroll
            for (int tt = 0; tt < TPR; ++tt) segv[c][tt] = 0.f;
#pragma unroll
        for (int tt = 0; tt < TPR; ++tt) swv[tt] = 0.f;
        if (lane < PPB) {
#pragma unroll
            for (int tt = 0; tt < TPR; ++tt) {
                const int p = h * WW + tt * PPB + lane;
#pragma unroll
                for (int c = 0; c < KK; ++c)
                    segv[c][tt] = seg[(size_t)n * KK * PIX + (size_t)c * PIX + p];
                swv[tt] = swgt[(size_t)n * PIX + p];
            }
            if (wv_ == 0) {
#pragma unroll
                for (int tt = 0; tt < TPR; ++tt)
#pragma unroll
                    for (int c = 0; c < KK; ++c)
                        rV[c] += swv[tt] * segv[c][tt];
            }
        }

#pragma unroll
        for (int tt = 0; tt < TPR; ++tt) {
            const int ti = s * TPR + tt;
            // ---- continuous prefetch of next weight tile ----
            if (ti + 1 < NTILE) stage_w(cur ^ 1, ti + 1);

            // ---- compute tile from LDS; fold into rA ----
            if (lane < PPB) {
                unsigned idx[9];
#pragma unroll
                for (int m = 0; m < 9; ++m)
                    idx[m] = (unsigned)((s + m) * ROWF + tt * PPB + lane);
                const float* lwp = lds_w + cur * WSLAB + lane * NWIN;
                float acc[KK] = {0.f, 0.f, 0.f, 0.f};
                switch (wv_) {
                    case 0:  do_taps<0, 10>(lwp, psg_lds, idx, acc); break;
                    case 1:  do_taps<10, 20>(lwp, psg_lds, idx, acc); break;
                    case 2:  do_taps<20, 30>(lwp, psg_lds, idx, acc); break;
                    case 3:  do_taps<30, 40>(lwp, psg_lds, idx, acc); break;
                    case 4:  do_taps<40, 50>(lwp, psg_lds, idx, acc); break;
                    case 5:  do_taps<50, 60>(lwp, psg_lds, idx, acc); break;
                    case 6:  do_taps<60, 70>(lwp, psg_lds, idx, acc); break;
                    default: do_taps<70, 81>(lwp, psg_lds, idx, acc); break;
                }
#pragma unroll
                for (int c = 0; c < KK; ++c) rA[c] += acc[c] * segv[c][tt];
            }
            __syncthreads();   // prefetch drained (hidden under compute); buf free
            cur ^= 1;
        }
    }

    // ---- single block-end reduction ----
    float vals[8] = { rA[0], rA[1], rA[2], rA[3], rV[0], rV[1], rV[2], rV[3] };
#pragma unroll
    for (int i = 0; i < 8; ++i) {
        float v = vals[i];
#pragma unroll
        for (int off = 32; off > 0; off >>= 1) v += __shfl_down(v, off, 64);
        if (lane == 0) lred[wv_][i] = v;
    }
    __syncthreads();
    if (tid < 8) {
        float ssum = 0.f;
#pragma unroll
        for (int w = 0; w < 8; ++w) ssum += lred[w][tid];
        part[(size_t)b * 8 + tid] = ssum;
    }
}

__global__ __launch_bounds__(256) void ncuts_stage2(
    const float* __restrict__ part, float* __restrict__ out)
{
    const int n   = blockIdx.x;
    const int tid = threadIdx.x;

    float vals[8] = {0.f, 0.f, 0.f, 0.f, 0.f, 0.f, 0.f, 0.f};
    for (int bb = tid; bb < GPI; bb += 256) {       // 32 entries per image
        const float* q = part + ((size_t)(n * GPI + bb)) * 8;
#pragma unroll
        for (int i = 0; i < 8; ++i) vals[i] += q[i];
    }

    __shared__ float lred[4][8];
    const int lane = tid & 63;
    const int wv_  = tid >> 6;
#pragma unroll
    for (int i = 0; i < 8; ++i) {
        float v = vals[i];
#pragma unroll
        for (int off = 32; off > 0; off >>= 1) v += __shfl_down(v, off, 64);
        if (lane == 0) lred[wv_][i] = v;
    }
    __syncthreads();
    if (tid == 0) {
        float assoc = 0.f;
#pragma unroll
        for (int k = 0; k < 4; ++k) {
            const float A = lred[0][k] + lred[1][k] + lred[2][k] + lred[3][k];
            const float V = lred[0][4 + k] + lred[1][4 + k] + lred[2][4 + k] + lred[3][4 + k];
            assoc += A / V;
        }
        out[n] = 4.0f - assoc;
    }
}

extern "C" void kernel_launch(void* const* d_in, const int* in_sizes, int n_in,
                              void* d_out, int out_size, void* d_ws, size_t ws_size,
                              hipStream_t stream) {
    const float* seg  = (const float*)d_in[0];
    const float* pseg = (const float*)d_in[1];
    const float* wgt  = (const float*)d_in[2];
    const float* swgt = (const float*)d_in[3];
    float* out  = (float*)d_out;
    float* part = (float*)d_ws;   // 256 blocks * 8 floats = 8192 B

    ncuts_stage1<<<NBLK, TPB, 0, stream>>>(seg, pseg, wgt, swgt, part);
    ncuts_stage2<<<NN, 256, 0, stream>>>(part, out);
}